// Round 3
// baseline (1937.250 us; speedup 1.0000x reference)
//
#include <hip/hip_runtime.h>
#include <hip/hip_bf16.h>

// TripletGCNModel on MI355X (gfx950), bf16-MFMA, atomic-free aggregation.
//
// N=20000, E=100000, DN=DE=256, DH=512, L=2.
// GEMM1 (Ex768 @ 768x512, gathered A) -> m1
// GEMM2 (Ex512 @ 512x1280): dual-N blocks (bn<4) pair cols c and c+768 so the
//   epilogue writes xm = relu(z1)+relu(z2) straight to dst-sorted xs[pos[r]];
//   bn in {4,5} produce new_e. No atomics.
// k_aggregate: CSR segment mean over xs -> aggb (bf16).
// GEMM3 (Nx512 @ 512x512), GEMM4 (Nx512 @ 512x256 + residual).
//
// All GEMMs: BM=BN=128, BK=32, 256 thr = 4 waves (2x2), 16x16x32 bf16 MFMA.
// LDS tiles [128][32] bf16, 16B-chunk XOR swizzle (chunk ^= (r^r>>2)&3):
// linear LDS dest via global_load_lds + inverse-swizzled SOURCE + swizzled read.

typedef __bf16 bf16x8 __attribute__((ext_vector_type(8)));
typedef float f32x4 __attribute__((ext_vector_type(4)));

static constexpr int kN = 20000;
static constexpr int kE = 100000;

__device__ __forceinline__ int swz4(int r) { return (r ^ (r >> 2)) & 3; }

__device__ __forceinline__ void gload16(const void* g, unsigned short* l) {
  __builtin_amdgcn_global_load_lds(
      (const __attribute__((address_space(1))) unsigned int*)g,
      (__attribute__((address_space(3))) unsigned int*)(void*)l, 16, 0, 0);
}

// ---------------- CSR build ----------------

__global__ void k_counti(const int* __restrict__ dstI, int* __restrict__ cntI, int n) {
  int i = blockIdx.x * 256 + threadIdx.x;
  if (i < n) atomicAdd(&cntI[dstI[i]], 1);
}

__global__ __launch_bounds__(256) void k_scan(const int* __restrict__ cntI,
                                              int* __restrict__ rowptr,
                                              int* __restrict__ offs) {
  __shared__ int ss[256];
  int t = threadIdx.x;
  const int CH = (kN + 255) / 256;  // 79
  int base = t * CH;
  int s = 0;
  for (int i = 0; i < CH; ++i) { int j = base + i; if (j < kN) s += cntI[j]; }
  ss[t] = s;
  __syncthreads();
  if (t == 0) {
    int a = 0;
    for (int i = 0; i < 256; ++i) { int v = ss[i]; ss[i] = a; a += v; }
  }
  __syncthreads();
  int run = ss[t];
  for (int i = 0; i < CH; ++i) {
    int j = base + i;
    if (j < kN) { rowptr[j] = run; offs[j] = run; run += cntI[j]; }
  }
}

__global__ void k_assign(const int* __restrict__ dstI, int* __restrict__ offs,
                         int* __restrict__ pos, int n) {
  int i = blockIdx.x * 256 + threadIdx.x;
  if (i < n) pos[i] = atomicAdd(&offs[dstI[i]], 1);
}

// block per node: mean over its sorted xs rows, bf16 out. thread t owns cols 2t,2t+1.
__global__ __launch_bounds__(256) void k_aggregate(
    const __hip_bfloat16* __restrict__ xs, const int* __restrict__ rowptr,
    const int* __restrict__ cntI, __hip_bfloat16* __restrict__ aggb) {
  int node = blockIdx.x;
  int t = threadIdx.x;
  int start = rowptr[node], deg = cntI[node];
  float a0 = 0.f, a1 = 0.f;
  const unsigned int* p = (const unsigned int*)xs + (size_t)start * 256 + t;
  for (int r = 0; r < deg; ++r, p += 256) {
    unsigned int v = *p;
    a0 += __uint_as_float(v << 16);
    a1 += __uint_as_float(v & 0xffff0000u);
  }
  float inv = 1.0f / fmaxf((float)deg, 1.0f);
  a0 *= inv; a1 *= inv;
  __hip_bfloat16 b0 = __float2bfloat16(a0), b1 = __float2bfloat16(a1);
  unsigned int w = ((unsigned int)(*(unsigned short*)&b1) << 16) | (*(unsigned short*)&b0);
  ((unsigned int*)aggb)[(size_t)node * 256 + t] = w;
}

// ---------------- weight/input prep ----------------

__global__ void k_cvt_wT(const float* __restrict__ W, __hip_bfloat16* __restrict__ Wt,
                         int Kd, int Nd, int total) {
  int i = blockIdx.x * 256 + threadIdx.x;
  if (i >= total) return;
  int k = i % Kd; int t = i / Kd; int nn = t % Nd; int l = t / Nd;
  Wt[i] = __float2bfloat16(W[((size_t)l * Kd + k) * Nd + nn]);
}

__global__ void k_cvt4(const float* __restrict__ in, __hip_bfloat16* __restrict__ out, int n4) {
  int i = blockIdx.x * 256 + threadIdx.x;
  if (i >= n4) return;
  float4 v = ((const float4*)in)[i];
  out[4 * i + 0] = __float2bfloat16(v.x);
  out[4 * i + 1] = __float2bfloat16(v.y);
  out[4 * i + 2] = __float2bfloat16(v.z);
  out[4 * i + 3] = __float2bfloat16(v.w);
}

// ---------------- the GEMM ----------------
// MODE 1: A = gather [xb[dst]|eb|xb[src]], relu -> outb (bf16, ld 512)
// MODE 2: dual (bn<4): xm = relu(z1)+relu(z2) -> xs[pos[r]][col] (bf16)
//         single (bn 4,5): new_e relu -> outb(bf16,L0) / outf(f32,last)
// MODE 3: relu -> outb (bf16, ld 512)
// MODE 4: z += resid; L0: relu -> outf(f32)+outb(bf16); last: -> outf(f32). ld 256
template <int MODE, bool L0>
__global__ __launch_bounds__(256) void gemm_k(
    const __hip_bfloat16* __restrict__ A, const __hip_bfloat16* __restrict__ xb,
    const __hip_bfloat16* __restrict__ eb, const int* __restrict__ srcI,
    const int* __restrict__ dstI, const int* __restrict__ pos,
    const __hip_bfloat16* __restrict__ Bt, const float* __restrict__ bias,
    int M, int K, __hip_bfloat16* __restrict__ xs,
    __hip_bfloat16* __restrict__ outb, float* __restrict__ outf,
    const float* __restrict__ resid) {
  constexpr int SMEM_USH = (MODE == 2) ? 12288 : 8192;  // 24KB : 16KB
  __shared__ alignas(16) unsigned short smem[SMEM_USH];

  const int tid = threadIdx.x;
  const int wave = tid >> 6, lane = tid & 63;
  const int hi = lane >> 4, lo = lane & 15;
  const int wr = wave >> 1, wc = wave & 1;
  const int bm = blockIdx.x, bn = blockIdx.y;
  const bool dual = (MODE == 2) && (bn < 4);

  // staging geometry: thread owns slot (tid&3) of local rows rloc, rloc+64
  const int rloc = tid >> 2, slot = tid & 3;

  int rowA[2], ndst[2], nsrc[2];
#pragma unroll
  for (int is = 0; is < 2; ++is) {
    int rg = bm * 128 + is * 64 + rloc;
    rg = (rg < M) ? rg : (M - 1);
    rowA[is] = rg;
    if (MODE == 1) { ndst[is] = dstI[rg]; nsrc[is] = srcI[rg]; }
  }
  int nb1, nb2 = 0;
  if (MODE == 2) {
    if (bn < 4) { nb1 = bn * 128; nb2 = 768 + bn * 128; }
    else        { nb1 = 512 + (bn - 4) * 128; }
  } else {
    nb1 = bn * 128;
  }

  f32x4 acc[4][4], acc2[4][4];
#pragma unroll
  for (int a = 0; a < 4; ++a)
#pragma unroll
    for (int b = 0; b < 4; ++b)
#pragma unroll
      for (int i = 0; i < 4; ++i) { acc[a][b][i] = 0.0f; if (MODE == 2) acc2[a][b][i] = 0.0f; }

  const int kSteps = K >> 5;
  for (int kt = 0; kt < kSteps; ++kt) {
    // ---- stage via global_load_lds (linear LDS dest, pre-swizzled source) ----
#pragma unroll
    for (int is = 0; is < 2; ++is) {
      int r = is * 64 + rloc;
      int col = (kt << 5) + ((slot ^ swz4(r)) << 3);
      const __hip_bfloat16* src;
      if (MODE == 1) {
        if (col < 256)      src = xb + (size_t)ndst[is] * 256 + col;
        else if (col < 512) src = eb + (size_t)rowA[is] * 256 + (col - 256);
        else                src = xb + (size_t)nsrc[is] * 256 + (col - 512);
      } else {
        src = A + (size_t)rowA[is] * K + col;
      }
      gload16(src, &smem[(is * 256 + tid) * 8]);
    }
#pragma unroll
    for (int is = 0; is < 2; ++is) {
      int r = is * 64 + rloc;
      int col = (kt << 5) + ((slot ^ swz4(r)) << 3);
      gload16(Bt + (size_t)(nb1 + r) * K + col, &smem[4096 + (is * 256 + tid) * 8]);
    }
    if (dual) {
#pragma unroll
      for (int is = 0; is < 2; ++is) {
        int r = is * 64 + rloc;
        int col = (kt << 5) + ((slot ^ swz4(r)) << 3);
        gload16(Bt + (size_t)(nb2 + r) * K + col, &smem[8192 + (is * 256 + tid) * 8]);
      }
    }
    __syncthreads();

    // ---- fragments + MFMA ----
    bf16x8 af[4], b1f[4], b2f[4];
#pragma unroll
    for (int mi = 0; mi < 4; ++mi) {
      int r = wr * 64 + mi * 16 + lo;
      af[mi] = *(const bf16x8*)(&smem[r * 32 + ((hi ^ swz4(r)) << 3)]);
    }
#pragma unroll
    for (int ni = 0; ni < 4; ++ni) {
      int r = wc * 64 + ni * 16 + lo;
      b1f[ni] = *(const bf16x8*)(&smem[4096 + r * 32 + ((hi ^ swz4(r)) << 3)]);
      if (dual)
        b2f[ni] = *(const bf16x8*)(&smem[8192 + r * 32 + ((hi ^ swz4(r)) << 3)]);
    }
#pragma unroll
    for (int mi = 0; mi < 4; ++mi)
#pragma unroll
      for (int ni = 0; ni < 4; ++ni) {
        acc[mi][ni] = __builtin_amdgcn_mfma_f32_16x16x32_bf16(af[mi], b1f[ni], acc[mi][ni], 0, 0, 0);
        if (MODE == 2) {
          if (dual)
            acc2[mi][ni] = __builtin_amdgcn_mfma_f32_16x16x32_bf16(af[mi], b2f[ni], acc2[mi][ni], 0, 0, 0);
        }
      }
    __syncthreads();
  }

  // ---- epilogue: D row = mi*16 + 4*hi + i, col = ni*16 + lo (m89 layout) ----
#pragma unroll
  for (int mi = 0; mi < 4; ++mi) {
    int rowb = bm * 128 + wr * 64 + mi * 16 + 4 * hi;
#pragma unroll
    for (int i = 0; i < 4; ++i) {
      int r = rowb + i;
      if (r >= M) continue;
      int pr = 0;
      if (MODE == 2) { if (dual) pr = pos[r]; }
#pragma unroll
      for (int ni = 0; ni < 4; ++ni) {
        int cl = wc * 64 + ni * 16 + lo;  // 0..127 within slice
        float z = acc[mi][ni][i];
        if (MODE == 1) {
          int col = bn * 128 + cl;
          z = fmaxf(z + bias[col], 0.0f);
          outb[(size_t)r * 512 + col] = __float2bfloat16(z);
        } else if (MODE == 3) {
          int col = bn * 128 + cl;
          z = fmaxf(z + bias[col], 0.0f);
          outb[(size_t)r * 512 + col] = __float2bfloat16(z);
        } else if (MODE == 4) {
          int col = bn * 128 + cl;  // < 256
          z += bias[col];
          z += resid[(size_t)r * 256 + col];
          if (L0) {
            z = fmaxf(z, 0.0f);
            outf[(size_t)r * 256 + col] = z;
            outb[(size_t)r * 256 + col] = __float2bfloat16(z);
          } else {
            outf[(size_t)r * 256 + col] = z;
          }
        } else {  // MODE 2
          if (dual) {
            int col = bn * 128 + cl;  // xm col in [0,512)
            float z1 = fmaxf(z + bias[col], 0.0f);
            float z2 = fmaxf(acc2[mi][ni][i] + bias[col + 768], 0.0f);
            xs[(size_t)pr * 512 + col] = __float2bfloat16(z1 + z2);
          } else {
            int col = 512 + (bn - 4) * 128 + cl;
            z = fmaxf(z + bias[col], 0.0f);
            int ec = col - 512;
            if (L0) outb[(size_t)r * 256 + ec] = __float2bfloat16(z);
            else    outf[(size_t)r * 256 + ec] = z;
          }
        }
      }
    }
  }
}

// ---------------- launch ----------------

extern "C" void kernel_launch(void* const* d_in, const int* in_sizes, int n_in,
                              void* d_out, int out_size, void* d_ws, size_t ws_size,
                              hipStream_t stream) {
  const float* x0  = (const float*)d_in[0];
  const float* e0  = (const float*)d_in[1];
  const int*   idx = (const int*)d_in[2];
  const float* W1a = (const float*)d_in[3];
  const float* b1a = (const float*)d_in[4];
  const float* W1b = (const float*)d_in[5];
  const float* b1b = (const float*)d_in[6];
  const float* W2a = (const float*)d_in[7];
  const float* b2a = (const float*)d_in[8];
  const float* W2b = (const float*)d_in[9];
  const float* b2b = (const float*)d_in[10];
  const int* srcI = idx;
  const int* dstI = idx + kE;
  float* outx = (float*)d_out;                      // N x 256
  float* oute = (float*)d_out + (size_t)kN * 256;   // E x 256

  char* ws = (char*)d_ws;
  size_t off = 0;
  auto alloc = [&](size_t bytes) -> char* {
    char* p = ws + off;
    off += (bytes + 255) & ~(size_t)255;
    return p;
  };
  __hip_bfloat16* W1aT = (__hip_bfloat16*)alloc((size_t)2 * 512 * 768 * 2);
  __hip_bfloat16* W1bT = (__hip_bfloat16*)alloc((size_t)2 * 1280 * 512 * 2);
  __hip_bfloat16* W2aT = (__hip_bfloat16*)alloc((size_t)2 * 512 * 512 * 2);
  __hip_bfloat16* W2bT = (__hip_bfloat16*)alloc((size_t)2 * 256 * 512 * 2);
  __hip_bfloat16* xbuf = (__hip_bfloat16*)alloc((size_t)kN * 256 * 2);  // x0b, then x1b
  __hip_bfloat16* ebuf = (__hip_bfloat16*)alloc((size_t)kE * 256 * 2);  // e0b, then e1b
  float*          x1f  = (float*)alloc((size_t)kN * 256 * 4);
  __hip_bfloat16* m1   = (__hip_bfloat16*)alloc((size_t)kE * 512 * 2);
  __hip_bfloat16* xs   = (__hip_bfloat16*)alloc((size_t)kE * 512 * 2);  // dst-sorted xm
  __hip_bfloat16* aggb = (__hip_bfloat16*)alloc((size_t)kN * 512 * 2);
  __hip_bfloat16* hbuf = (__hip_bfloat16*)alloc((size_t)kN * 512 * 2);
  int*            cntI = (int*)alloc((size_t)kN * 4);
  int*            rowptr = (int*)alloc((size_t)kN * 4);
  int*            offs = (int*)alloc((size_t)kN * 4);
  int*            pos  = (int*)alloc((size_t)kE * 4);

  // ---- CSR over dst (layer-invariant) ----
  (void)hipMemsetAsync(cntI, 0, (size_t)kN * 4, stream);
  k_counti<<<(kE + 255) / 256, 256, 0, stream>>>(dstI, cntI, kE);
  k_scan<<<1, 256, 0, stream>>>(cntI, rowptr, offs);
  k_assign<<<(kE + 255) / 256, 256, 0, stream>>>(dstI, offs, pos, kE);

  // ---- weight / input conversion ----
  k_cvt_wT<<<(2 * 768 * 512 + 255) / 256, 256, 0, stream>>>(W1a, W1aT, 768, 512, 2 * 768 * 512);
  k_cvt_wT<<<(2 * 512 * 1280 + 255) / 256, 256, 0, stream>>>(W1b, W1bT, 512, 1280, 2 * 512 * 1280);
  k_cvt_wT<<<(2 * 512 * 512 + 255) / 256, 256, 0, stream>>>(W2a, W2aT, 512, 512, 2 * 512 * 512);
  k_cvt_wT<<<(2 * 512 * 256 + 255) / 256, 256, 0, stream>>>(W2b, W2bT, 512, 256, 2 * 512 * 256);
  k_cvt4<<<(kN * 256 / 4 + 255) / 256, 256, 0, stream>>>(x0, xbuf, kN * 256 / 4);
  k_cvt4<<<(kE * 256 / 4 + 255) / 256, 256, 0, stream>>>(e0, ebuf, kE * 256 / 4);

  dim3 blk(256);
  int gmE = (kE + 127) / 128;  // 782
  int gmN = (kN + 127) / 128;  // 157

  // ---- layer 0 ----
  gemm_k<1, true><<<dim3(gmE, 4), blk, 0, stream>>>(
      nullptr, xbuf, ebuf, srcI, dstI, nullptr, W1aT, b1a, kE, 768,
      nullptr, m1, nullptr, nullptr);
  gemm_k<2, true><<<dim3(gmE, 6), blk, 0, stream>>>(
      m1, nullptr, nullptr, nullptr, nullptr, pos, W1bT, b1b, kE, 512,
      xs, ebuf, nullptr, nullptr);
  k_aggregate<<<kN, 256, 0, stream>>>(xs, rowptr, cntI, aggb);
  gemm_k<3, true><<<dim3(gmN, 4), blk, 0, stream>>>(
      aggb, nullptr, nullptr, nullptr, nullptr, nullptr, W2aT, b2a, kN, 512,
      nullptr, hbuf, nullptr, nullptr);
  gemm_k<4, true><<<dim3(gmN, 2), blk, 0, stream>>>(
      hbuf, nullptr, nullptr, nullptr, nullptr, nullptr, W2bT, b2b, kN, 512,
      nullptr, xbuf, x1f, x0);

  // ---- layer 1 (last) ----
  gemm_k<1, false><<<dim3(gmE, 4), blk, 0, stream>>>(
      nullptr, xbuf, ebuf, srcI, dstI, nullptr, W1aT + (size_t)512 * 768, b1a + 512, kE, 768,
      nullptr, m1, nullptr, nullptr);
  gemm_k<2, false><<<dim3(gmE, 6), blk, 0, stream>>>(
      m1, nullptr, nullptr, nullptr, nullptr, pos, W1bT + (size_t)1280 * 512, b1b + 1280, kE, 512,
      xs, nullptr, oute, nullptr);
  k_aggregate<<<kN, 256, 0, stream>>>(xs, rowptr, cntI, aggb);
  gemm_k<3, false><<<dim3(gmN, 4), blk, 0, stream>>>(
      aggb, nullptr, nullptr, nullptr, nullptr, nullptr, W2aT + (size_t)512 * 512, b2a + 512, kN, 512,
      nullptr, hbuf, nullptr, nullptr);
  gemm_k<4, false><<<dim3(gmN, 2), blk, 0, stream>>>(
      hbuf, nullptr, nullptr, nullptr, nullptr, nullptr, W2bT + (size_t)256 * 512, b2b + 256, kN, 512,
      nullptr, nullptr, outx, x1f);
}

// Round 4
// 1098.017 us; speedup vs baseline: 1.7643x; 1.7643x over previous
//
#include <hip/hip_runtime.h>
#include <hip/hip_bf16.h>

// TripletGCNModel on MI355X (gfx950), bf16-MFMA, atomic-free aggregation.
//
// N=20000, E=100000, DN=DE=256, DH=512, L=2.
// GEMM1 (Ex768 @ 768x512, gathered A) -> m1
// GEMM2 split: gemm2_dual pairs output cols c and c+768 (BN=64 per half,
//   acc 16xf32x4 so occupancy stays at 3 waves/SIMD) and writes
//   xm = relu(z1)+relu(z2) to dst-sorted xs[pos[r]]; MODE 5 computes the
//   e-slice (cols 512:768) as a plain GEMM. No atomics.
// k_aggregate: CSR segment mean over xs -> aggb (bf16).
// GEMM3 (Nx512 @ 512x512), GEMM4 (Nx512 @ 512x256 + residual).
//
// All GEMMs: BM=128, BK=32, 256 thr = 4 waves, 16x16x32 bf16 MFMA.
// LDS tiles [rows][32] bf16, 16B-chunk XOR swizzle (chunk ^= (r^r>>2)&3):
// linear LDS dest via global_load_lds + inverse-swizzled SOURCE + swizzled read.
// All grids flat 1-D with chunked-bijective XCD swizzle (m204), bn-fastest
// so each A panel is consumed by one XCD's L2.

typedef __bf16 bf16x8 __attribute__((ext_vector_type(8)));
typedef float f32x4 __attribute__((ext_vector_type(4)));

static constexpr int kN = 20000;
static constexpr int kE = 100000;

__device__ __forceinline__ int swz4(int r) { return (r ^ (r >> 2)) & 3; }

__device__ __forceinline__ void gload16(const void* g, unsigned short* l) {
  __builtin_amdgcn_global_load_lds(
      (const __attribute__((address_space(1))) unsigned int*)g,
      (__attribute__((address_space(3))) unsigned int*)(void*)l, 16, 0, 0);
}

// chunked-bijective XCD swizzle (m204): xcd = f%8 gets a contiguous work range.
__device__ __forceinline__ void unflat(int f, int total, int nbn, int& bm, int& bn) {
  int q = total >> 3, r8 = total & 7;
  int xcd = f & 7, local = f >> 3;
  int g = (xcd < r8 ? xcd * (q + 1) : r8 * (q + 1) + (xcd - r8) * q) + local;
  bm = g / nbn; bn = g % nbn;
}

// ---------------- CSR build ----------------

__global__ void k_counti(const int* __restrict__ dstI, int* __restrict__ cntI, int n) {
  int i = blockIdx.x * 256 + threadIdx.x;
  if (i < n) atomicAdd(&cntI[dstI[i]], 1);
}

__global__ __launch_bounds__(256) void k_scan(const int* __restrict__ cntI,
                                              int* __restrict__ rowptr,
                                              int* __restrict__ offs) {
  __shared__ int ss[256];
  int t = threadIdx.x;
  const int CH = (kN + 255) / 256;  // 79
  int base = t * CH;
  int s = 0;
  for (int i = 0; i < CH; ++i) { int j = base + i; if (j < kN) s += cntI[j]; }
  ss[t] = s;
  __syncthreads();
  if (t == 0) {
    int a = 0;
    for (int i = 0; i < 256; ++i) { int v = ss[i]; ss[i] = a; a += v; }
  }
  __syncthreads();
  int run = ss[t];
  for (int i = 0; i < CH; ++i) {
    int j = base + i;
    if (j < kN) { rowptr[j] = run; offs[j] = run; run += cntI[j]; }
  }
}

__global__ void k_assign(const int* __restrict__ dstI, int* __restrict__ offs,
                         int* __restrict__ pos, int n) {
  int i = blockIdx.x * 256 + threadIdx.x;
  if (i < n) pos[i] = atomicAdd(&offs[dstI[i]], 1);
}

// block per node: mean over its sorted xs rows, bf16 out. thread t owns cols 2t,2t+1.
__global__ __launch_bounds__(256) void k_aggregate(
    const __hip_bfloat16* __restrict__ xs, const int* __restrict__ rowptr,
    const int* __restrict__ cntI, __hip_bfloat16* __restrict__ aggb) {
  int node = blockIdx.x;
  int t = threadIdx.x;
  int start = rowptr[node], deg = cntI[node];
  float a0 = 0.f, a1 = 0.f;
  const unsigned int* p = (const unsigned int*)xs + (size_t)start * 256 + t;
  for (int r = 0; r < deg; ++r, p += 256) {
    unsigned int v = *p;
    a0 += __uint_as_float(v << 16);
    a1 += __uint_as_float(v & 0xffff0000u);
  }
  float inv = 1.0f / fmaxf((float)deg, 1.0f);
  a0 *= inv; a1 *= inv;
  __hip_bfloat16 b0 = __float2bfloat16(a0), b1 = __float2bfloat16(a1);
  unsigned int w = ((unsigned int)(*(unsigned short*)&b1) << 16) | (*(unsigned short*)&b0);
  ((unsigned int*)aggb)[(size_t)node * 256 + t] = w;
}

// ---------------- weight/input prep ----------------

__global__ void k_cvt_wT(const float* __restrict__ W, __hip_bfloat16* __restrict__ Wt,
                         int Kd, int Nd, int total) {
  int i = blockIdx.x * 256 + threadIdx.x;
  if (i >= total) return;
  int k = i % Kd; int t = i / Kd; int nn = t % Nd; int l = t / Nd;
  Wt[i] = __float2bfloat16(W[((size_t)l * Kd + k) * Nd + nn]);
}

__global__ void k_cvt4(const float* __restrict__ in, __hip_bfloat16* __restrict__ out, int n4) {
  int i = blockIdx.x * 256 + threadIdx.x;
  if (i >= n4) return;
  float4 v = ((const float4*)in)[i];
  out[4 * i + 0] = __float2bfloat16(v.x);
  out[4 * i + 1] = __float2bfloat16(v.y);
  out[4 * i + 2] = __float2bfloat16(v.z);
  out[4 * i + 3] = __float2bfloat16(v.w);
}

// ---------------- GEMM2 dual kernel ----------------
// BM=128, BN=64 per half. Wave (wr,wc): rows wr*64, cols wc*32. K=512.
// xm = relu(z1 + b[col]) + relu(z2 + b[col+768]) -> xs[pos[r]][col], col=bn*64+...
template <bool L0>
__global__ __launch_bounds__(256, 3) void gemm2_dual(
    const __hip_bfloat16* __restrict__ A, const int* __restrict__ pos,
    const __hip_bfloat16* __restrict__ Bt, const float* __restrict__ bias,
    int M, __hip_bfloat16* __restrict__ xs, int total) {
  __shared__ alignas(16) unsigned short smem[8192];  // A:[0,4096) B1:[4096,6144) B2:[6144,8192)
  constexpr int K = 512;
  int bm, bn;
  unflat(blockIdx.x, total, 8, bm, bn);

  const int tid = threadIdx.x;
  const int wave = tid >> 6, lane = tid & 63;
  const int hi = lane >> 4, lo = lane & 15;
  const int wr = wave >> 1, wc = wave & 1;
  const int rloc = tid >> 2, slot = tid & 3;

  int rowA[2];
#pragma unroll
  for (int is = 0; is < 2; ++is) {
    int rg = bm * 128 + is * 64 + rloc;
    rowA[is] = (rg < M) ? rg : (M - 1);
  }
  const int nb1 = bn * 64, nb2 = 768 + bn * 64;

  f32x4 acc[4][2], acc2[4][2];
#pragma unroll
  for (int a = 0; a < 4; ++a)
#pragma unroll
    for (int b = 0; b < 2; ++b)
#pragma unroll
      for (int i = 0; i < 4; ++i) { acc[a][b][i] = 0.0f; acc2[a][b][i] = 0.0f; }

  for (int kt = 0; kt < (K >> 5); ++kt) {
#pragma unroll
    for (int is = 0; is < 2; ++is) {
      int r = is * 64 + rloc;
      int col = (kt << 5) + ((slot ^ swz4(r)) << 3);
      gload16(A + (size_t)rowA[is] * K + col, &smem[(is * 256 + tid) * 8]);
    }
    {
      int r = rloc & 63;  // rloc in [0,64)
      int col = (kt << 5) + ((slot ^ swz4(r)) << 3);
      gload16(Bt + (size_t)(nb1 + r) * K + col, &smem[4096 + tid * 8]);
      gload16(Bt + (size_t)(nb2 + r) * K + col, &smem[6144 + tid * 8]);
    }
    __syncthreads();

    bf16x8 af[4], b1f[2], b2f[2];
#pragma unroll
    for (int mi = 0; mi < 4; ++mi) {
      int r = wr * 64 + mi * 16 + lo;
      af[mi] = *(const bf16x8*)(&smem[r * 32 + ((hi ^ swz4(r)) << 3)]);
    }
#pragma unroll
    for (int ni = 0; ni < 2; ++ni) {
      int r = wc * 32 + ni * 16 + lo;
      int o = r * 32 + ((hi ^ swz4(r)) << 3);
      b1f[ni] = *(const bf16x8*)(&smem[4096 + o]);
      b2f[ni] = *(const bf16x8*)(&smem[6144 + o]);
    }
#pragma unroll
    for (int mi = 0; mi < 4; ++mi)
#pragma unroll
      for (int ni = 0; ni < 2; ++ni) {
        acc[mi][ni]  = __builtin_amdgcn_mfma_f32_16x16x32_bf16(af[mi], b1f[ni], acc[mi][ni], 0, 0, 0);
        acc2[mi][ni] = __builtin_amdgcn_mfma_f32_16x16x32_bf16(af[mi], b2f[ni], acc2[mi][ni], 0, 0, 0);
      }
    __syncthreads();
  }

#pragma unroll
  for (int mi = 0; mi < 4; ++mi) {
    int rowb = bm * 128 + wr * 64 + mi * 16 + 4 * hi;
#pragma unroll
    for (int i = 0; i < 4; ++i) {
      int r = rowb + i;
      if (r >= M) continue;
      int pr = pos[r];
#pragma unroll
      for (int ni = 0; ni < 2; ++ni) {
        int col = bn * 64 + wc * 32 + ni * 16 + lo;
        float z1 = fmaxf(acc[mi][ni][i] + bias[col], 0.0f);
        float z2 = fmaxf(acc2[mi][ni][i] + bias[col + 768], 0.0f);
        xs[(size_t)pr * 512 + col] = __float2bfloat16(z1 + z2);
      }
    }
  }
}

// ---------------- generic GEMM ----------------
// MODE 1: A = gather [xb[dst]|eb|xb[src]], relu -> outb (bf16, ld 512)
// MODE 3: relu -> outb (bf16, ld 512)
// MODE 4: z += resid; L0: relu -> outf(f32)+outb(bf16); last: -> outf(f32). ld 256
// MODE 5: e-slice: relu -> L0 outb(bf16) / last outf(f32). ld 256
template <int MODE, bool L0>
__global__ __launch_bounds__(256, 3) void gemm_k(
    const __hip_bfloat16* __restrict__ A, const __hip_bfloat16* __restrict__ xb,
    const __hip_bfloat16* __restrict__ eb, const int* __restrict__ srcI,
    const int* __restrict__ dstI, const __hip_bfloat16* __restrict__ Bt,
    const float* __restrict__ bias, int M, int K,
    __hip_bfloat16* __restrict__ outb, float* __restrict__ outf,
    const float* __restrict__ resid, int nbn, int total) {
  __shared__ alignas(16) unsigned short smem[8192];  // A: [0,4096), B: [4096,8192)
  int bm, bn;
  unflat(blockIdx.x, total, nbn, bm, bn);

  const int tid = threadIdx.x;
  const int wave = tid >> 6, lane = tid & 63;
  const int hi = lane >> 4, lo = lane & 15;
  const int wr = wave >> 1, wc = wave & 1;
  const int rloc = tid >> 2, slot = tid & 3;

  int rowA[2], ndst[2], nsrc[2];
#pragma unroll
  for (int is = 0; is < 2; ++is) {
    int rg = bm * 128 + is * 64 + rloc;
    rg = (rg < M) ? rg : (M - 1);
    rowA[is] = rg;
    if (MODE == 1) { ndst[is] = dstI[rg]; nsrc[is] = srcI[rg]; }
  }
  const int nb1 = bn * 128;

  f32x4 acc[4][4];
#pragma unroll
  for (int a = 0; a < 4; ++a)
#pragma unroll
    for (int b = 0; b < 4; ++b)
#pragma unroll
      for (int i = 0; i < 4; ++i) acc[a][b][i] = 0.0f;

  const int kSteps = K >> 5;
  for (int kt = 0; kt < kSteps; ++kt) {
#pragma unroll
    for (int is = 0; is < 2; ++is) {
      int r = is * 64 + rloc;
      int col = (kt << 5) + ((slot ^ swz4(r)) << 3);
      const __hip_bfloat16* src;
      if (MODE == 1) {
        if (col < 256)      src = xb + (size_t)ndst[is] * 256 + col;
        else if (col < 512) src = eb + (size_t)rowA[is] * 256 + (col - 256);
        else                src = xb + (size_t)nsrc[is] * 256 + (col - 512);
      } else {
        src = A + (size_t)rowA[is] * K + col;
      }
      gload16(src, &smem[(is * 256 + tid) * 8]);
    }
#pragma unroll
    for (int is = 0; is < 2; ++is) {
      int r = is * 64 + rloc;
      int col = (kt << 5) + ((slot ^ swz4(r)) << 3);
      gload16(Bt + (size_t)(nb1 + r) * K + col, &smem[4096 + (is * 256 + tid) * 8]);
    }
    __syncthreads();

    bf16x8 af[4], bfr[4];
#pragma unroll
    for (int mi = 0; mi < 4; ++mi) {
      int r = wr * 64 + mi * 16 + lo;
      af[mi] = *(const bf16x8*)(&smem[r * 32 + ((hi ^ swz4(r)) << 3)]);
    }
#pragma unroll
    for (int ni = 0; ni < 4; ++ni) {
      int r = wc * 64 + ni * 16 + lo;
      bfr[ni] = *(const bf16x8*)(&smem[4096 + r * 32 + ((hi ^ swz4(r)) << 3)]);
    }
#pragma unroll
    for (int mi = 0; mi < 4; ++mi)
#pragma unroll
      for (int ni = 0; ni < 4; ++ni)
        acc[mi][ni] = __builtin_amdgcn_mfma_f32_16x16x32_bf16(af[mi], bfr[ni], acc[mi][ni], 0, 0, 0);
    __syncthreads();
  }

#pragma unroll
  for (int mi = 0; mi < 4; ++mi) {
    int rowb = bm * 128 + wr * 64 + mi * 16 + 4 * hi;
#pragma unroll
    for (int i = 0; i < 4; ++i) {
      int r = rowb + i;
      if (r >= M) continue;
#pragma unroll
      for (int ni = 0; ni < 4; ++ni) {
        int cl = wc * 64 + ni * 16 + lo;
        int col = bn * 128 + cl;
        float z = acc[mi][ni][i] + bias[col];
        if (MODE == 1 || MODE == 3) {
          z = fmaxf(z, 0.0f);
          outb[(size_t)r * 512 + col] = __float2bfloat16(z);
        } else if (MODE == 4) {
          z += resid[(size_t)r * 256 + col];
          if (L0) {
            z = fmaxf(z, 0.0f);
            outf[(size_t)r * 256 + col] = z;
            outb[(size_t)r * 256 + col] = __float2bfloat16(z);
          } else {
            outf[(size_t)r * 256 + col] = z;
          }
        } else {  // MODE 5
          z = fmaxf(z, 0.0f);
          if (L0) outb[(size_t)r * 256 + col] = __float2bfloat16(z);
          else    outf[(size_t)r * 256 + col] = z;
        }
      }
    }
  }
}

// ---------------- launch ----------------

extern "C" void kernel_launch(void* const* d_in, const int* in_sizes, int n_in,
                              void* d_out, int out_size, void* d_ws, size_t ws_size,
                              hipStream_t stream) {
  const float* x0  = (const float*)d_in[0];
  const float* e0  = (const float*)d_in[1];
  const int*   idx = (const int*)d_in[2];
  const float* W1a = (const float*)d_in[3];
  const float* b1a = (const float*)d_in[4];
  const float* W1b = (const float*)d_in[5];
  const float* b1b = (const float*)d_in[6];
  const float* W2a = (const float*)d_in[7];
  const float* b2a = (const float*)d_in[8];
  const float* W2b = (const float*)d_in[9];
  const float* b2b = (const float*)d_in[10];
  const int* srcI = idx;
  const int* dstI = idx + kE;
  float* outx = (float*)d_out;                      // N x 256
  float* oute = (float*)d_out + (size_t)kN * 256;   // E x 256

  char* ws = (char*)d_ws;
  size_t off = 0;
  auto alloc = [&](size_t bytes) -> char* {
    char* p = ws + off;
    off += (bytes + 255) & ~(size_t)255;
    return p;
  };
  __hip_bfloat16* W1aT = (__hip_bfloat16*)alloc((size_t)2 * 512 * 768 * 2);
  __hip_bfloat16* W1bT = (__hip_bfloat16*)alloc((size_t)2 * 1280 * 512 * 2);
  __hip_bfloat16* W2aT = (__hip_bfloat16*)alloc((size_t)2 * 512 * 512 * 2);
  __hip_bfloat16* W2bT = (__hip_bfloat16*)alloc((size_t)2 * 256 * 512 * 2);
  __hip_bfloat16* xbuf = (__hip_bfloat16*)alloc((size_t)kN * 256 * 2);  // x0b, then x1b
  __hip_bfloat16* ebuf = (__hip_bfloat16*)alloc((size_t)kE * 256 * 2);  // e0b, then e1b
  float*          x1f  = (float*)alloc((size_t)kN * 256 * 4);
  __hip_bfloat16* m1   = (__hip_bfloat16*)alloc((size_t)kE * 512 * 2);
  __hip_bfloat16* xs   = (__hip_bfloat16*)alloc((size_t)kE * 512 * 2);  // dst-sorted xm
  __hip_bfloat16* aggb = (__hip_bfloat16*)alloc((size_t)kN * 512 * 2);
  __hip_bfloat16* hbuf = (__hip_bfloat16*)alloc((size_t)kN * 512 * 2);
  int*            cntI = (int*)alloc((size_t)kN * 4);
  int*            rowptr = (int*)alloc((size_t)kN * 4);
  int*            offs = (int*)alloc((size_t)kN * 4);
  int*            pos  = (int*)alloc((size_t)kE * 4);

  // ---- CSR over dst (layer-invariant) ----
  (void)hipMemsetAsync(cntI, 0, (size_t)kN * 4, stream);
  k_counti<<<(kE + 255) / 256, 256, 0, stream>>>(dstI, cntI, kE);
  k_scan<<<1, 256, 0, stream>>>(cntI, rowptr, offs);
  k_assign<<<(kE + 255) / 256, 256, 0, stream>>>(dstI, offs, pos, kE);

  // ---- weight / input conversion ----
  k_cvt_wT<<<(2 * 768 * 512 + 255) / 256, 256, 0, stream>>>(W1a, W1aT, 768, 512, 2 * 768 * 512);
  k_cvt_wT<<<(2 * 512 * 1280 + 255) / 256, 256, 0, stream>>>(W1b, W1bT, 512, 1280, 2 * 512 * 1280);
  k_cvt_wT<<<(2 * 512 * 512 + 255) / 256, 256, 0, stream>>>(W2a, W2aT, 512, 512, 2 * 512 * 512);
  k_cvt_wT<<<(2 * 512 * 256 + 255) / 256, 256, 0, stream>>>(W2b, W2bT, 512, 256, 2 * 512 * 256);
  k_cvt4<<<(kN * 256 / 4 + 255) / 256, 256, 0, stream>>>(x0, xbuf, kN * 256 / 4);
  k_cvt4<<<(kE * 256 / 4 + 255) / 256, 256, 0, stream>>>(e0, ebuf, kE * 256 / 4);

  dim3 blk(256);
  const int gmE = (kE + 127) / 128;  // 782
  const int gmN = (kN + 127) / 128;  // 157
  const int t1 = gmE * 4, t2d = gmE * 8, t5 = gmE * 2, t3 = gmN * 4, t4 = gmN * 2;

  // ---- layer 0 ----
  gemm_k<1, true><<<t1, blk, 0, stream>>>(
      nullptr, xbuf, ebuf, srcI, dstI, W1aT, b1a, kE, 768, m1, nullptr, nullptr, 4, t1);
  gemm2_dual<true><<<t2d, blk, 0, stream>>>(m1, pos, W1bT, b1b, kE, xs, t2d);
  gemm_k<5, true><<<t5, blk, 0, stream>>>(
      m1, nullptr, nullptr, nullptr, nullptr, W1bT + (size_t)512 * 512, b1b + 512, kE, 512,
      ebuf, nullptr, nullptr, 2, t5);
  k_aggregate<<<kN, 256, 0, stream>>>(xs, rowptr, cntI, aggb);
  gemm_k<3, true><<<t3, blk, 0, stream>>>(
      aggb, nullptr, nullptr, nullptr, nullptr, W2aT, b2a, kN, 512, hbuf, nullptr, nullptr, 4, t3);
  gemm_k<4, true><<<t4, blk, 0, stream>>>(
      hbuf, nullptr, nullptr, nullptr, nullptr, W2bT, b2b, kN, 512, xbuf, x1f, x0, 2, t4);

  // ---- layer 1 (last) ----
  gemm_k<1, false><<<t1, blk, 0, stream>>>(
      nullptr, xbuf, ebuf, srcI, dstI, W1aT + (size_t)512 * 768, b1a + 512, kE, 768,
      m1, nullptr, nullptr, 4, t1);
  gemm2_dual<false><<<t2d, blk, 0, stream>>>(
      m1, pos, W1bT + (size_t)1280 * 512, b1b + 1280, kE, xs, t2d);
  gemm_k<5, false><<<t5, blk, 0, stream>>>(
      m1, nullptr, nullptr, nullptr, nullptr, W1bT + (size_t)1280 * 512 + (size_t)512 * 512,
      b1b + 1280 + 512, kE, 512, nullptr, oute, nullptr, 2, t5);
  k_aggregate<<<kN, 256, 0, stream>>>(xs, rowptr, cntI, aggb);
  gemm_k<3, false><<<t3, blk, 0, stream>>>(
      aggb, nullptr, nullptr, nullptr, nullptr, W2aT + (size_t)512 * 512, b2a + 512, kN, 512,
      hbuf, nullptr, nullptr, 4, t3);
  gemm_k<4, false><<<t4, blk, 0, stream>>>(
      hbuf, nullptr, nullptr, nullptr, nullptr, W2bT + (size_t)256 * 512, b2b + 256, kN, 512,
      nullptr, outx, x1f, 2, t4);
}